// Round 1
// baseline (910.167 us; speedup 1.0000x reference)
//
#include <hip/hip_runtime.h>
#include <math.h>

constexpr int CW = 3125;   // valid width
constexpr int CC = 256;    // channels
constexpr int CB = 4;      // batch
constexpr int NHh = 8;     // heads
constexpr int KDd = 64;    // qk head dim
constexpr int HDd = 32;    // v head dim

__global__ __launch_bounds__(256) void copy_x(const float* __restrict__ src,
                                              float* __restrict__ dst, int n) {
  int i = blockIdx.x * 256 + threadIdx.x;
  if (i < n) dst[i] = src[i];
}

// C[o][p] = BN(sum_c W[o][c] * X[c][p]);  p = b*L + l, X read from xcur (b,256,CW), 0 for l>=CW
// MODE 0: qk -> out0=q,out1=k  laid out (b,NH,L,64)
// MODE 1: v  -> out0 (b,256,L), out1 (b,NH,L,32)
// MODE 2: proj -> out0 (b,256,CW)   (L must equal CW)
template <int MODE>
__global__ __launch_bounds__(256) void conv1x1_bn(
    const float* __restrict__ X, const float* __restrict__ W,
    const float* __restrict__ G, const float* __restrict__ Bb,
    const float* __restrict__ M, const float* __restrict__ V,
    float* __restrict__ out0, float* __restrict__ out1, int L) {
  const int P = CB * L;
  __shared__ float sW[16][65];
  __shared__ float sX[16][65];
  int tid = threadIdx.x;
  int tx = tid & 15, ty = tid >> 4;
  int oBase = blockIdx.y * 64;
  int pBase = blockIdx.x * 64;
  float acc[4][4] = {};
  for (int k0 = 0; k0 < CC; k0 += 16) {
#pragma unroll
    for (int r = 0; r < 4; r++) {
      int ii = tid + r * 256;
      int kk = ii & 15, oo = ii >> 4;
      sW[kk][oo] = W[(size_t)(oBase + oo) * CC + k0 + kk];
    }
#pragma unroll
    for (int r = 0; r < 4; r++) {
      int ii = tid + r * 256;
      int kk = ii >> 6, pp = ii & 63;
      int p = pBase + pp;
      float val = 0.f;
      if (p < P) {
        int bI = p / L, l = p - bI * L;
        if (l < CW) val = X[((size_t)bI * CC + (k0 + kk)) * CW + l];
      }
      sX[kk][pp] = val;
    }
    __syncthreads();
#pragma unroll
    for (int kk = 0; kk < 16; kk++) {
      float wv[4], xv[4];
#pragma unroll
      for (int i = 0; i < 4; i++) wv[i] = sW[kk][i * 16 + ty];
#pragma unroll
      for (int j = 0; j < 4; j++) xv[j] = sX[kk][j * 16 + tx];
#pragma unroll
      for (int i = 0; i < 4; i++)
#pragma unroll
        for (int j = 0; j < 4; j++) acc[i][j] += wv[i] * xv[j];
    }
    __syncthreads();
  }
#pragma unroll
  for (int i = 0; i < 4; i++) {
    int o = oBase + i * 16 + ty;
    float s = G[o] * rsqrtf(V[o] + 1e-5f);
    float sh = Bb[o] - M[o] * s;
#pragma unroll
    for (int j = 0; j < 4; j++) {
      int p = pBase + j * 16 + tx;
      if (p >= P) continue;
      int bI = p / L, l = p - bI * L;
      float y = acc[i][j] * s + sh;
      if (MODE == 0) {
        int nh = o >> 7, sp = (o >> 6) & 1, d = o & 63;
        float* dst = sp ? out1 : out0;
        dst[(((size_t)(bI * NHh + nh)) * L + l) * KDd + d] = y;
      } else if (MODE == 1) {
        out0[((size_t)bI * CC + o) * L + l] = y;
        out1[(((size_t)(bI * NHh + (o >> 5))) * L + l) * HDd + (o & 31)] = y;
      } else {
        out0[((size_t)bI * CC + o) * CW + l] = y;
      }
    }
  }
}

// One 64-lane wave per group of BASE positions spaced by `stride`.
// score[J][j] = (1/8) sum_d q[d,l_j]*k[d,l_J]; softmax over j; out[l_J] = sum_j w*v[l_j]
template <int BASE>
__global__ __launch_bounds__(256) void attn_level(
    const float* __restrict__ q, const float* __restrict__ k,
    const float* __restrict__ vin, float* __restrict__ vout,
    int L, int stride, int gpb) {
  int lane = threadIdx.x & 63;
  int gid = blockIdx.x * 4 + (threadIdx.x >> 6);
  int bh = gid / gpb;
  int g = gid - bh * gpb;
  int i0 = g / stride;
  int k2 = g - i0 * stride;
  size_t base0 = (size_t)bh * L + (size_t)i0 * BASE * stride + k2;

  float qv[BASE], kv[BASE];
#pragma unroll
  for (int j = 0; j < BASE; j++) {
    size_t l = base0 + (size_t)j * stride;
    qv[j] = q[l * KDd + lane];
    kv[j] = k[l * KDd + lane];
  }
  float sc[BASE * BASE];
#pragma unroll
  for (int J = 0; J < BASE; J++)
#pragma unroll
    for (int j = 0; j < BASE; j++) sc[J * BASE + j] = kv[J] * qv[j];
#pragma unroll
  for (int off = 1; off < 64; off <<= 1) {
#pragma unroll
    for (int t = 0; t < BASE * BASE; t++) sc[t] += __shfl_xor(sc[t], off, 64);
  }
  // softmax over j for each J (scale 1/8), all lanes redundantly
#pragma unroll
  for (int J = 0; J < BASE; J++) {
    float mx = sc[J * BASE + 0];
#pragma unroll
    for (int j = 1; j < BASE; j++) mx = fmaxf(mx, sc[J * BASE + j]);
    float sum = 0.f;
#pragma unroll
    for (int j = 0; j < BASE; j++) {
      float e = __expf((sc[J * BASE + j] - mx) * 0.125f);
      sc[J * BASE + j] = e;
      sum += e;
    }
    float inv = 1.f / sum;
#pragma unroll
    for (int j = 0; j < BASE; j++) sc[J * BASE + j] *= inv;
  }
  // PV
  int dd = lane & 31, half = lane >> 5;
  float vv[BASE];
#pragma unroll
  for (int j = 0; j < BASE; j++)
    vv[j] = vin[(base0 + (size_t)j * stride) * HDd + dd];
#pragma unroll
  for (int J = 0; J < BASE; J++) {
    if ((J & 1) == half) {
      float acc = 0.f;
#pragma unroll
      for (int j = 0; j < BASE; j++) acc += sc[J * BASE + j] * vv[j];
      vout[(base0 + (size_t)J * stride) * HDd + dd] = acc;
    }
  }
}

// xcur += v2 + BN(dwconv3(v0)), truncated to l<CW
__global__ __launch_bounds__(256) void combine(
    float* __restrict__ xcur, const float* __restrict__ v0cl,
    const float* __restrict__ vfin, const float* __restrict__ peW,
    const float* __restrict__ G, const float* __restrict__ Bb,
    const float* __restrict__ M, const float* __restrict__ V, int L) {
  int idx = blockIdx.x * 256 + threadIdx.x;
  if (idx >= CB * CC * CW) return;
  int l = idx % CW;
  int t = idx / CW;
  int ch = t % CC;
  int bI = t / CC;
  const float* vrow = v0cl + ((size_t)bI * CC + ch) * L;
  float left = (l > 0) ? vrow[l - 1] : 0.f;
  float mid = vrow[l];
  float right = (l + 1 < L) ? vrow[l + 1] : 0.f;
  float conv = left * peW[ch * 3 + 0] + mid * peW[ch * 3 + 1] + right * peW[ch * 3 + 2];
  float s = G[ch] * rsqrtf(V[ch] + 1e-5f);
  float pe = conv * s + (Bb[ch] - M[ch] * s);
  float v2 = vfin[(((size_t)(bI * NHh + (ch >> 5))) * L + l) * HDd + (ch & 31)];
  xcur[idx] += v2 + pe;
}

extern "C" void kernel_launch(void* const* d_in, const int* in_sizes, int n_in,
                              void* d_out, int out_size, void* d_ws, size_t ws_size,
                              hipStream_t stream) {
  const float* x = (const float*)d_in[0];
  const float* qk_W = (const float*)d_in[1];
  const float* qk_g = (const float*)d_in[2];
  const float* qk_b = (const float*)d_in[3];
  const float* qk_m = (const float*)d_in[4];
  const float* qk_v = (const float*)d_in[5];
  const float* v_W = (const float*)d_in[6];
  const float* v_g = (const float*)d_in[7];
  const float* v_b = (const float*)d_in[8];
  const float* v_m = (const float*)d_in[9];
  const float* v_v = (const float*)d_in[10];
  const float* pe_W = (const float*)d_in[11];
  const float* pe_g = (const float*)d_in[12];
  const float* pe_b = (const float*)d_in[13];
  const float* pe_m = (const float*)d_in[14];
  const float* pe_v = (const float*)d_in[15];
  const float* proj_W = (const float*)d_in[16];
  const float* proj_g = (const float*)d_in[17];
  const float* proj_b = (const float*)d_in[18];
  const float* proj_m = (const float*)d_in[19];
  const float* proj_v = (const float*)d_in[20];

  char* ws = (char*)d_ws;
  size_t off = 0;
  auto alloc = [&](size_t bytes) {
    char* p = ws + off;
    off += (bytes + 255) & ~(size_t)255;
    return (float*)p;
  };
  const int Lmax = 4096;
  float* xcur = alloc((size_t)CB * CC * CW * 4);
  float* qbuf = alloc((size_t)CB * NHh * Lmax * KDd * 4);
  float* kbuf = alloc((size_t)CB * NHh * Lmax * KDd * 4);
  float* v0cl = alloc((size_t)CB * CC * Lmax * 4);
  float* v0lhd = alloc((size_t)CB * CC * Lmax * 4);
  float* vA = alloc((size_t)CB * CC * Lmax * 4);
  float* vB = alloc((size_t)CB * CC * Lmax * 4);
  (void)ws_size;

  int nElems = CB * CC * CW;
  copy_x<<<(nElems + 255) / 256, 256, 0, stream>>>(x, xcur, nElems);

  const int bases[2] = {5, 4};
  const int ns[2] = {5, 6};
  const int Ls[2] = {3125, 4096};
  for (int blk = 0; blk < 2; blk++) {
    int base = bases[blk], n = ns[blk], L = Ls[blk];
    int P = CB * L;
    dim3 gqk((P + 63) / 64, 1024 / 64);
    conv1x1_bn<0><<<gqk, 256, 0, stream>>>(
        xcur, qk_W + (size_t)blk * 1024 * CC, qk_g + blk * 1024,
        qk_b + blk * 1024, qk_m + blk * 1024, qk_v + blk * 1024, qbuf, kbuf, L);
    dim3 gv((P + 63) / 64, CC / 64);
    conv1x1_bn<1><<<gv, 256, 0, stream>>>(
        xcur, v_W + (size_t)blk * CC * CC, v_g + blk * CC, v_b + blk * CC,
        v_m + blk * CC, v_v + blk * CC, v0cl, v0lhd, L);

    const float* vin = v0lhd;
    float* pp[2] = {vA, vB};
    int stride = 1;
    for (int i = 0; i < n - 1; i++) stride *= base;
    for (int i = 0; i < n; i++) {
      float* vo = pp[i & 1];
      int gpb = L / base;
      int totalg = CB * NHh * gpb;
      if (base == 5)
        attn_level<5><<<totalg / 4, 256, 0, stream>>>(qbuf, kbuf, vin, vo, L, stride, gpb);
      else
        attn_level<4><<<totalg / 4, 256, 0, stream>>>(qbuf, kbuf, vin, vo, L, stride, gpb);
      vin = vo;
      stride /= base;
    }
    combine<<<(nElems + 255) / 256, 256, 0, stream>>>(
        xcur, v0cl, vin, pe_W + (size_t)blk * CC * 3, pe_g + blk * CC,
        pe_b + blk * CC, pe_m + blk * CC, pe_v + blk * CC, L);
  }
  dim3 gp((CB * CW + 63) / 64, CC / 64);
  conv1x1_bn<2><<<gp, 256, 0, stream>>>(xcur, proj_W, proj_g, proj_b, proj_m,
                                        proj_v, (float*)d_out, nullptr, CW);
}

// Round 2
// 657.017 us; speedup vs baseline: 1.3853x; 1.3853x over previous
//
#include <hip/hip_runtime.h>
#include <math.h>

constexpr int CW = 3125;   // valid width
constexpr int CC = 256;    // channels
constexpr int CB = 4;      // batch
constexpr int NHh = 8;     // heads
constexpr int KDd = 64;    // qk head dim
constexpr int HDd = 32;    // v head dim

typedef __attribute__((ext_vector_type(8))) short short8;
typedef __attribute__((ext_vector_type(4))) float f32x4;
typedef __attribute__((ext_vector_type(4))) unsigned int uint4v;

__device__ inline unsigned short f2bf(float x) {
  unsigned int u = __float_as_uint(x);
  unsigned int r = u + 0x7FFFu + ((u >> 16) & 1u);
  return (unsigned short)(r >> 16);
}

__device__ inline void gload_lds16(const void* g, void* l) {
  typedef __attribute__((address_space(3))) unsigned int lds_u32;
  typedef const __attribute__((address_space(1))) unsigned int glob_u32;
  __builtin_amdgcn_global_load_lds((glob_u32*)g, (lds_u32*)l, 16, 0, 0);
}

__global__ __launch_bounds__(256) void copy_x(const float* __restrict__ src,
                                              float* __restrict__ dst, int n) {
  int i = blockIdx.x * 256 + threadIdx.x;
  if (i < n) dst[i] = src[i];
}

// Build weight staging image: [otile][ktile=16][kchunk=4][o=128][16B]
// ktiles 0-7 = W (for x-hi), 8-15 = same W again (for x-lo).
__global__ __launch_bounds__(256) void prep_w(const float* __restrict__ W0, int O0,
                                              const float* __restrict__ W1,
                                              unsigned short* __restrict__ img,
                                              int Ototal) {
  int t = blockIdx.x * 256 + threadIdx.x;
  if (t >= Ototal * 32) return;
  int o = t >> 5, ch = t & 31;           // ch: 8-channel chunk index (k = ch*8..+8)
  const float* row = (o < O0) ? (W0 + (size_t)o * CC) : (W1 + (size_t)(o - O0) * CC);
  unsigned short h[8];
#pragma unroll
  for (int j = 0; j < 8; j++) h[j] = f2bf(row[ch * 8 + j]);
  uint4v v;
  v[0] = (unsigned)h[0] | ((unsigned)h[1] << 16);
  v[1] = (unsigned)h[2] | ((unsigned)h[3] << 16);
  v[2] = (unsigned)h[4] | ((unsigned)h[5] << 16);
  v[3] = (unsigned)h[6] | ((unsigned)h[7] << 16);
  int otile = o >> 7, oo = o & 127;
  int ktile = ch >> 2, kchunk = ch & 3;
  uint4v* img4 = (uint4v*)img;
  size_t idx = ((size_t)otile * 16 + ktile) * 512 + kchunk * 128 + oo;
  img4[idx] = v;
  img4[idx + 8 * 512] = v;  // lo copy
}

// Build x staging image from xcur [CB][CC][CW] (fp32), split hi/lo bf16.
// Image: [ptile][ktile=16][kchunk=4][p=128][16B]; ktile<8: hi(k=c), >=8: lo(k=c+256)
__global__ __launch_bounds__(256) void prep_x(const float* __restrict__ X,
                                              unsigned short* __restrict__ img,
                                              int L, int P) {
  int ptile = blockIdx.x, cq = blockIdx.y;  // cq: 64-channel group
  int c0 = cq * 64;
  __shared__ float sX[64][129];
  int tid = threadIdx.x;
  for (int i = tid; i < 64 * 128; i += 256) {
    int cc = i >> 7, pp = i & 127;
    int p = ptile * 128 + pp;
    float val = 0.f;
    if (p < P) {
      int bI = p / L, l = p - bI * L;
      if (l < CW) val = X[((size_t)bI * CC + (c0 + cc)) * CW + l];
    }
    sX[cc][pp] = val;
  }
  __syncthreads();
  uint4v* img4 = (uint4v*)img;
  for (int i = tid; i < 1024; i += 256) {
    int ch = i >> 7, pp = i & 127;  // ch: chunk of 8 channels within the 64
    float f[8];
    unsigned short h[8], lo[8];
#pragma unroll
    for (int j = 0; j < 8; j++) f[j] = sX[ch * 8 + j][pp];
#pragma unroll
    for (int j = 0; j < 8; j++) {
      h[j] = f2bf(f[j]);
      float hif = __uint_as_float((unsigned)h[j] << 16);
      lo[j] = f2bf(f[j] - hif);
    }
    uint4v vh, vl;
    vh[0] = (unsigned)h[0] | ((unsigned)h[1] << 16);
    vh[1] = (unsigned)h[2] | ((unsigned)h[3] << 16);
    vh[2] = (unsigned)h[4] | ((unsigned)h[5] << 16);
    vh[3] = (unsigned)h[6] | ((unsigned)h[7] << 16);
    vl[0] = (unsigned)lo[0] | ((unsigned)lo[1] << 16);
    vl[1] = (unsigned)lo[2] | ((unsigned)lo[3] << 16);
    vl[2] = (unsigned)lo[4] | ((unsigned)lo[5] << 16);
    vl[3] = (unsigned)lo[6] | ((unsigned)lo[7] << 16);
    int ktile = cq * 2 + (ch >> 2), kchunk = ch & 3;
    size_t idx = ((size_t)ptile * 16 + ktile) * 512 + kchunk * 128 + pp;
    img4[idx] = vh;
    img4[idx + 8 * 512] = vl;
  }
}

// MFMA GEMM: C[o][p] = BN(sum_k W[o][k]*X[k][p]), K=512 (hi+lo), tile 128x128.
// MODE 0: fused qkv (O=1280): o<1024 -> q/k (b,NH,L,64); o>=1024 -> v0cl (b,256,L) + v0lhd (b,NH,L,32)
// MODE 2: proj (O=256) -> out (b,256,CW)
template <int MODE>
__global__ __launch_bounds__(256) void gemm_bn(
    const unsigned short* __restrict__ Aimg, const unsigned short* __restrict__ Ximg,
    const float* __restrict__ G0, const float* __restrict__ B0,
    const float* __restrict__ M0, const float* __restrict__ V0,
    const float* __restrict__ G1, const float* __restrict__ B1,
    const float* __restrict__ M1, const float* __restrict__ V1,
    float* __restrict__ q, float* __restrict__ k, float* __restrict__ v0cl,
    float* __restrict__ v0lhd, float* __restrict__ out, int L, int P) {
  __shared__ __align__(16) unsigned short sA[4096];
  __shared__ __align__(16) unsigned short sB[4096];
  int tid = threadIdx.x;
  int wid = tid >> 6, lane = tid & 63;
  int wr = wid >> 1, wc = wid & 1;
  int otile = blockIdx.y, ptile = blockIdx.x;
  f32x4 acc[4][4] = {};
  size_t aBase = ((size_t)otile * 16) * 4096;
  size_t bBase = ((size_t)ptile * 16) * 4096;
  int r = lane & 15, kb = lane >> 4;
  for (int kt = 0; kt < 16; kt++) {
    __syncthreads();
#pragma unroll
    for (int i = 0; i < 4; i++) {
      int c = wid * 4 + i;
      if (c < 8) {
        gload_lds16(Aimg + aBase + kt * 4096 + c * 512 + lane * 8, sA + c * 512 + lane * 8);
      } else {
        gload_lds16(Ximg + bBase + kt * 4096 + (c - 8) * 512 + lane * 8,
                    sB + (c - 8) * 512 + lane * 8);
      }
    }
    __syncthreads();
    short8 a[4], b[4];
#pragma unroll
    for (int mi = 0; mi < 4; mi++)
      a[mi] = *(const short8*)&sA[kb * 1024 + (wr * 64 + mi * 16 + r) * 8];
#pragma unroll
    for (int ni = 0; ni < 4; ni++)
      b[ni] = *(const short8*)&sB[kb * 1024 + (wc * 64 + ni * 16 + r) * 8];
#pragma unroll
    for (int mi = 0; mi < 4; mi++)
#pragma unroll
      for (int ni = 0; ni < 4; ni++)
        acc[mi][ni] = __builtin_amdgcn_mfma_f32_16x16x32_bf16(a[mi], b[ni], acc[mi][ni], 0, 0, 0);
  }
  int r4 = lane >> 4, cl = lane & 15;
#pragma unroll
  for (int mi = 0; mi < 4; mi++) {
#pragma unroll
    for (int reg = 0; reg < 4; reg++) {
      int o = otile * 128 + wr * 64 + mi * 16 + r4 * 4 + reg;
      float s, sh;
      if (MODE == 0 && o >= 1024) {
        int oc = o - 1024;
        s = G1[oc] * rsqrtf(V1[oc] + 1e-5f);
        sh = B1[oc] - M1[oc] * s;
      } else {
        s = G0[o] * rsqrtf(V0[o] + 1e-5f);
        sh = B0[o] - M0[o] * s;
      }
#pragma unroll
      for (int ni = 0; ni < 4; ni++) {
        int p = ptile * 128 + wc * 64 + ni * 16 + cl;
        if (p >= P) continue;
        int bI = p / L, l = p - bI * L;
        float y = acc[mi][ni][reg] * s + sh;
        if (MODE == 0) {
          if (o < 1024) {
            int nh = o >> 7, sp = (o >> 6) & 1, d = o & 63;
            float* dst = sp ? k : q;
            dst[(((size_t)(bI * NHh + nh)) * L + l) * KDd + d] = y;
          } else {
            int oc = o - 1024;
            v0cl[((size_t)bI * CC + oc) * L + l] = y;
            v0lhd[(((size_t)(bI * NHh + (oc >> 5))) * L + l) * HDd + (oc & 31)] = y;
          }
        } else {
          if (l < CW) out[((size_t)bI * CC + o) * CW + l] = y;
        }
      }
    }
  }
}

// One 64-lane wave per group of BASE positions spaced by `stride`.
template <int BASE>
__global__ __launch_bounds__(256) void attn_level(
    const float* __restrict__ q, const float* __restrict__ k,
    const float* __restrict__ vin, float* __restrict__ vout,
    int L, int stride, int gpb) {
  int lane = threadIdx.x & 63;
  int gid = blockIdx.x * 4 + (threadIdx.x >> 6);
  int bh = gid / gpb;
  int g = gid - bh * gpb;
  int i0 = g / stride;
  int k2 = g - i0 * stride;
  size_t base0 = (size_t)bh * L + (size_t)i0 * BASE * stride + k2;

  float qv[BASE], kv[BASE];
#pragma unroll
  for (int j = 0; j < BASE; j++) {
    size_t l = base0 + (size_t)j * stride;
    qv[j] = q[l * KDd + lane];
    kv[j] = k[l * KDd + lane];
  }
  float sc[BASE * BASE];
#pragma unroll
  for (int J = 0; J < BASE; J++)
#pragma unroll
    for (int j = 0; j < BASE; j++) sc[J * BASE + j] = kv[J] * qv[j];
#pragma unroll
  for (int off = 1; off < 64; off <<= 1) {
#pragma unroll
    for (int t = 0; t < BASE * BASE; t++) sc[t] += __shfl_xor(sc[t], off, 64);
  }
#pragma unroll
  for (int J = 0; J < BASE; J++) {
    float mx = sc[J * BASE + 0];
#pragma unroll
    for (int j = 1; j < BASE; j++) mx = fmaxf(mx, sc[J * BASE + j]);
    float sum = 0.f;
#pragma unroll
    for (int j = 0; j < BASE; j++) {
      float e = __expf((sc[J * BASE + j] - mx) * 0.125f);
      sc[J * BASE + j] = e;
      sum += e;
    }
    float inv = 1.f / sum;
#pragma unroll
    for (int j = 0; j < BASE; j++) sc[J * BASE + j] *= inv;
  }
  int dd = lane & 31, half = lane >> 5;
  float vv[BASE];
#pragma unroll
  for (int j = 0; j < BASE; j++)
    vv[j] = vin[(base0 + (size_t)j * stride) * HDd + dd];
#pragma unroll
  for (int J = 0; J < BASE; J++) {
    if ((J & 1) == half) {
      float acc = 0.f;
#pragma unroll
      for (int j = 0; j < BASE; j++) acc += sc[J * BASE + j] * vv[j];
      vout[(base0 + (size_t)J * stride) * HDd + dd] = acc;
    }
  }
}

// xcur += v2 + BN(dwconv3(v0)), truncated to l<CW
__global__ __launch_bounds__(256) void combine(
    float* __restrict__ xcur, const float* __restrict__ v0cl,
    const float* __restrict__ vfin, const float* __restrict__ peW,
    const float* __restrict__ G, const float* __restrict__ Bb,
    const float* __restrict__ M, const float* __restrict__ V, int L) {
  int idx = blockIdx.x * 256 + threadIdx.x;
  if (idx >= CB * CC * CW) return;
  int l = idx % CW;
  int t = idx / CW;
  int ch = t % CC;
  int bI = t / CC;
  const float* vrow = v0cl + ((size_t)bI * CC + ch) * L;
  float left = (l > 0) ? vrow[l - 1] : 0.f;
  float mid = vrow[l];
  float right = (l + 1 < L) ? vrow[l + 1] : 0.f;
  float conv = left * peW[ch * 3 + 0] + mid * peW[ch * 3 + 1] + right * peW[ch * 3 + 2];
  float s = G[ch] * rsqrtf(V[ch] + 1e-5f);
  float pe = conv * s + (Bb[ch] - M[ch] * s);
  float v2 = vfin[(((size_t)(bI * NHh + (ch >> 5))) * L + l) * HDd + (ch & 31)];
  xcur[idx] += v2 + pe;
}

extern "C" void kernel_launch(void* const* d_in, const int* in_sizes, int n_in,
                              void* d_out, int out_size, void* d_ws, size_t ws_size,
                              hipStream_t stream) {
  const float* x = (const float*)d_in[0];
  const float* qk_W = (const float*)d_in[1];
  const float* qk_g = (const float*)d_in[2];
  const float* qk_b = (const float*)d_in[3];
  const float* qk_m = (const float*)d_in[4];
  const float* qk_v = (const float*)d_in[5];
  const float* v_W = (const float*)d_in[6];
  const float* v_g = (const float*)d_in[7];
  const float* v_b = (const float*)d_in[8];
  const float* v_m = (const float*)d_in[9];
  const float* v_v = (const float*)d_in[10];
  const float* pe_W = (const float*)d_in[11];
  const float* pe_g = (const float*)d_in[12];
  const float* pe_b = (const float*)d_in[13];
  const float* pe_m = (const float*)d_in[14];
  const float* pe_v = (const float*)d_in[15];
  const float* proj_W = (const float*)d_in[16];
  const float* proj_g = (const float*)d_in[17];
  const float* proj_b = (const float*)d_in[18];
  const float* proj_m = (const float*)d_in[19];
  const float* proj_v = (const float*)d_in[20];

  char* ws = (char*)d_ws;
  size_t off = 0;
  auto alloc = [&](size_t bytes) {
    char* p = ws + off;
    off += (bytes + 255) & ~(size_t)255;
    return (float*)p;
  };
  const int Lmax = 4096;
  float* xcur = alloc((size_t)CB * CC * CW * 4);
  float* qbuf = alloc((size_t)CB * NHh * Lmax * KDd * 4);
  float* kbuf = alloc((size_t)CB * NHh * Lmax * KDd * 4);
  float* v0cl = alloc((size_t)CB * CC * Lmax * 4);
  float* v0lhd = alloc((size_t)CB * CC * Lmax * 4);
  float* vA = alloc((size_t)CB * CC * Lmax * 4);   // also aliases Ximg during GEMM
  float* vB = alloc((size_t)CB * CC * Lmax * 4);
  unsigned short* Wimg = (unsigned short*)alloc((size_t)10 * 16 * 8192);
  unsigned short* Ximg = (unsigned short*)vA;  // 16 MB max, fits in vA's 16.78 MB
  (void)ws_size;

  int nElems = CB * CC * CW;
  copy_x<<<(nElems + 255) / 256, 256, 0, stream>>>(x, xcur, nElems);

  const int bases[2] = {5, 4};
  const int ns[2] = {5, 6};
  const int Ls[2] = {3125, 4096};
  for (int blk = 0; blk < 2; blk++) {
    int base = bases[blk], n = ns[blk], L = Ls[blk];
    int P = CB * L;
    int ptiles = (P + 127) / 128;
    // staging images
    prep_w<<<(1280 * 32 + 255) / 256, 256, 0, stream>>>(
        qk_W + (size_t)blk * 1024 * CC, 1024, v_W + (size_t)blk * CC * CC, Wimg, 1280);
    dim3 gx(ptiles, 4);
    prep_x<<<gx, 256, 0, stream>>>(xcur, Ximg, L, P);
    dim3 gg(ptiles, 10);
    gemm_bn<0><<<gg, 256, 0, stream>>>(
        Wimg, Ximg, qk_g + blk * 1024, qk_b + blk * 1024, qk_m + blk * 1024,
        qk_v + blk * 1024, v_g + blk * CC, v_b + blk * CC, v_m + blk * CC,
        v_v + blk * CC, qbuf, kbuf, v0cl, v0lhd, nullptr, L, P);

    const float* vin = v0lhd;
    float* pp[2] = {vA, vB};
    int stride = 1;
    for (int i = 0; i < n - 1; i++) stride *= base;
    for (int i = 0; i < n; i++) {
      float* vo = pp[i & 1];
      int gpb = L / base;
      int totalg = CB * NHh * gpb;
      if (base == 5)
        attn_level<5><<<totalg / 4, 256, 0, stream>>>(qbuf, kbuf, vin, vo, L, stride, gpb);
      else
        attn_level<4><<<totalg / 4, 256, 0, stream>>>(qbuf, kbuf, vin, vo, L, stride, gpb);
      vin = vo;
      stride /= base;
    }
    combine<<<(nElems + 255) / 256, 256, 0, stream>>>(
        xcur, v0cl, vin, pe_W + (size_t)blk * CC * 3, pe_g + blk * CC,
        pe_b + blk * CC, pe_m + blk * CC, pe_v + blk * CC, L);
  }
  // final projection
  {
    int L = CW, P = CB * CW;
    int ptiles = (P + 127) / 128;
    prep_w<<<(256 * 32 + 255) / 256, 256, 0, stream>>>(proj_W, 256, nullptr, Wimg, 256);
    dim3 gx(ptiles, 4);
    prep_x<<<gx, 256, 0, stream>>>(xcur, Ximg, L, P);
    dim3 gg(ptiles, 2);
    gemm_bn<2><<<gg, 256, 0, stream>>>(
        Wimg, Ximg, proj_g, proj_b, proj_m, proj_v, nullptr, nullptr, nullptr,
        nullptr, nullptr, nullptr, nullptr, nullptr, (float*)d_out, L, P);
  }
}

// Round 3
// 604.081 us; speedup vs baseline: 1.5067x; 1.0876x over previous
//
#include <hip/hip_runtime.h>
#include <math.h>

constexpr int CW = 3125;   // valid width
constexpr int CC = 256;    // channels
constexpr int CB = 4;      // batch
constexpr int NHh = 8;     // heads
constexpr int KDd = 64;    // qk head dim
constexpr int HDd = 32;    // v head dim

typedef __attribute__((ext_vector_type(8))) short short8;
typedef __attribute__((ext_vector_type(4))) float f32x4;
typedef __attribute__((ext_vector_type(4))) unsigned int uint4v;

__device__ inline unsigned short f2bf(float x) {
  unsigned int u = __float_as_uint(x);
  unsigned int r = u + 0x7FFFu + ((u >> 16) & 1u);
  return (unsigned short)(r >> 16);
}

__device__ inline void gload_lds16(const void* g, void* l) {
  typedef __attribute__((address_space(3))) unsigned int lds_u32;
  typedef const __attribute__((address_space(1))) unsigned int glob_u32;
  __builtin_amdgcn_global_load_lds((glob_u32*)g, (lds_u32*)l, 16, 0, 0);
}

// x (b,256,CW) channel-major  ->  xcur (b,CW,256) position-major, LDS-tiled transpose
__global__ __launch_bounds__(256) void transpose_x(const float* __restrict__ src,
                                                   float* __restrict__ dst) {
  __shared__ float sT[64][65];
  int l0 = blockIdx.x * 64, c0 = blockIdx.y * 64, bI = blockIdx.z;
  int tid = threadIdx.x;
  for (int i = tid; i < 4096; i += 256) {
    int ll = i & 63, cc = i >> 6;
    int l = l0 + ll;
    sT[cc][ll] = (l < CW) ? src[((size_t)bI * CC + c0 + cc) * CW + l] : 0.f;
  }
  __syncthreads();
  for (int i = tid; i < 4096; i += 256) {
    int cc = i & 63, ll = i >> 6;
    int l = l0 + ll;
    if (l < CW) dst[((size_t)bI * CW + l) * CC + c0 + cc] = sT[cc][ll];
  }
}

// Build weight staging image: [otile][ktile=16][kchunk=4][o=128][16B]
// ktiles 0-7 = W (for x-hi), 8-15 = same W again (for x-lo).
__global__ __launch_bounds__(256) void prep_w(const float* __restrict__ W0, int O0,
                                              const float* __restrict__ W1,
                                              unsigned short* __restrict__ img,
                                              int Ototal) {
  int t = blockIdx.x * 256 + threadIdx.x;
  if (t >= Ototal * 32) return;
  int o = t >> 5, ch = t & 31;
  const float* row = (o < O0) ? (W0 + (size_t)o * CC) : (W1 + (size_t)(o - O0) * CC);
  unsigned short h[8];
#pragma unroll
  for (int j = 0; j < 8; j++) h[j] = f2bf(row[ch * 8 + j]);
  uint4v v;
  v[0] = (unsigned)h[0] | ((unsigned)h[1] << 16);
  v[1] = (unsigned)h[2] | ((unsigned)h[3] << 16);
  v[2] = (unsigned)h[4] | ((unsigned)h[5] << 16);
  v[3] = (unsigned)h[6] | ((unsigned)h[7] << 16);
  int otile = o >> 7, oo = o & 127;
  int ktile = ch >> 2, kchunk = ch & 3;
  uint4v* img4 = (uint4v*)img;
  size_t idx = ((size_t)otile * 16 + ktile) * 512 + kchunk * 128 + oo;
  img4[idx] = v;
  img4[idx + 8 * 512] = v;  // lo copy
}

// Build x staging image from xcur (b,CW,256) position-major, split hi/lo bf16.
// Image: [ptile][ktile=16][kchunk=4][p=128][16B]; ktile<8: hi, >=8: lo
__global__ __launch_bounds__(256) void prep_x(const float* __restrict__ X,
                                              unsigned short* __restrict__ img,
                                              int L, int P) {
  int ptile = blockIdx.x, cq = blockIdx.y;  // cq: 64-channel group
  int c0 = cq * 64;
  __shared__ float sX[64][129];
  int tid = threadIdx.x;
  for (int i = tid; i < 64 * 128; i += 256) {
    int cc = i & 63, pp = i >> 6;
    int p = ptile * 128 + pp;
    float val = 0.f;
    if (p < P) {
      int bI = p / L, l = p - bI * L;
      if (l < CW) val = X[((size_t)bI * CW + l) * CC + c0 + cc];
    }
    sX[cc][pp] = val;
  }
  __syncthreads();
  uint4v* img4 = (uint4v*)img;
  for (int i = tid; i < 1024; i += 256) {
    int ch = i >> 7, pp = i & 127;
    float f[8];
    unsigned short h[8], lo[8];
#pragma unroll
    for (int j = 0; j < 8; j++) f[j] = sX[ch * 8 + j][pp];
#pragma unroll
    for (int j = 0; j < 8; j++) {
      h[j] = f2bf(f[j]);
      float hif = __uint_as_float((unsigned)h[j] << 16);
      lo[j] = f2bf(f[j] - hif);
    }
    uint4v vh, vl;
    vh[0] = (unsigned)h[0] | ((unsigned)h[1] << 16);
    vh[1] = (unsigned)h[2] | ((unsigned)h[3] << 16);
    vh[2] = (unsigned)h[4] | ((unsigned)h[5] << 16);
    vh[3] = (unsigned)h[6] | ((unsigned)h[7] << 16);
    vl[0] = (unsigned)lo[0] | ((unsigned)lo[1] << 16);
    vl[1] = (unsigned)lo[2] | ((unsigned)lo[3] << 16);
    vl[2] = (unsigned)lo[4] | ((unsigned)lo[5] << 16);
    vl[3] = (unsigned)lo[6] | ((unsigned)lo[7] << 16);
    int ktile = cq * 2 + (ch >> 2), kchunk = ch & 3;
    size_t idx = ((size_t)ptile * 16 + ktile) * 512 + kchunk * 128 + pp;
    img4[idx] = vh;
    img4[idx + 8 * 512] = vl;
  }
}

// MFMA GEMM: C[o][p] = BN(sum_k W[o][k]*X[k][p]), K=512 (hi+lo), tile 128x128.
// MODE 0 (SWAP=1): fused qkv (O=1280): o<1024 -> q/k (b,NH,L,64); o>=1024 -> v0pm (b,L,256)
// MODE 2 (SWAP=0): proj (O=256) -> out (b,256,CW)
template <int MODE>
__global__ __launch_bounds__(256) void gemm_bn(
    const unsigned short* __restrict__ Aimg, const unsigned short* __restrict__ Ximg,
    const float* __restrict__ G0, const float* __restrict__ B0,
    const float* __restrict__ M0, const float* __restrict__ V0,
    const float* __restrict__ G1, const float* __restrict__ B1,
    const float* __restrict__ M1, const float* __restrict__ V1,
    float* __restrict__ q, float* __restrict__ k, float* __restrict__ v0pm,
    float* __restrict__ out, int L, int P) {
  __shared__ __align__(16) unsigned short sA[4096];
  __shared__ __align__(16) unsigned short sB[4096];
  int tid = threadIdx.x;
  int wid = tid >> 6, lane = tid & 63;
  int wr = wid >> 1, wc = wid & 1;
  int otile = blockIdx.y, ptile = blockIdx.x;
  f32x4 acc[4][4] = {};
  size_t aBase = ((size_t)otile * 16) * 4096;
  size_t bBase = ((size_t)ptile * 16) * 4096;
  int r = lane & 15, kb = lane >> 4;
  for (int kt = 0; kt < 16; kt++) {
    __syncthreads();
#pragma unroll
    for (int i = 0; i < 4; i++) {
      int c = wid * 4 + i;
      if (c < 8) {
        gload_lds16(Aimg + aBase + kt * 4096 + c * 512 + lane * 8, sA + c * 512 + lane * 8);
      } else {
        gload_lds16(Ximg + bBase + kt * 4096 + (c - 8) * 512 + lane * 8,
                    sB + (c - 8) * 512 + lane * 8);
      }
    }
    __syncthreads();
    short8 a[4], b[4];
#pragma unroll
    for (int mi = 0; mi < 4; mi++)
      a[mi] = *(const short8*)&sA[kb * 1024 + (wr * 64 + mi * 16 + r) * 8];
#pragma unroll
    for (int ni = 0; ni < 4; ni++)
      b[ni] = *(const short8*)&sB[kb * 1024 + (wc * 64 + ni * 16 + r) * 8];
    if (MODE == 0) {
#pragma unroll
      for (int mi = 0; mi < 4; mi++)
#pragma unroll
        for (int ni = 0; ni < 4; ni++)
          acc[ni][mi] = __builtin_amdgcn_mfma_f32_16x16x32_bf16(b[ni], a[mi], acc[ni][mi], 0, 0, 0);
    } else {
#pragma unroll
      for (int mi = 0; mi < 4; mi++)
#pragma unroll
        for (int ni = 0; ni < 4; ni++)
          acc[mi][ni] = __builtin_amdgcn_mfma_f32_16x16x32_bf16(a[mi], b[ni], acc[mi][ni], 0, 0, 0);
    }
  }
  int cl = lane & 15, r4 = lane >> 4;
  if (MODE == 0) {
    // output row = p (r4*4+reg within ni), col = o (cl within mi)
#pragma unroll
    for (int mi = 0; mi < 4; mi++) {
      int o = otile * 128 + wr * 64 + mi * 16 + cl;
      float s, sh;
      if (o >= 1024) {
        int oc = o - 1024;
        s = G1[oc] * rsqrtf(V1[oc] + 1e-5f);
        sh = B1[oc] - M1[oc] * s;
      } else {
        s = G0[o] * rsqrtf(V0[o] + 1e-5f);
        sh = B0[o] - M0[o] * s;
      }
      int nh = (o & 1023) >> 7, sp = (o >> 6) & 1, d = o & 63;
      int oc = o - 1024;
#pragma unroll
      for (int ni = 0; ni < 4; ni++) {
#pragma unroll
        for (int reg = 0; reg < 4; reg++) {
          int p = ptile * 128 + wc * 64 + ni * 16 + r4 * 4 + reg;
          if (p >= P) continue;
          int bI = p / L, l = p - bI * L;
          float y = acc[ni][mi][reg] * s + sh;
          if (o < 1024) {
            float* dst = sp ? k : q;
            dst[(((size_t)(bI * NHh + nh)) * L + l) * KDd + d] = y;
          } else {
            v0pm[((size_t)bI * L + l) * CC + oc] = y;
          }
        }
      }
    }
  } else {
    // output row = o (r4*4+reg within mi), col = p (cl within ni)
#pragma unroll
    for (int mi = 0; mi < 4; mi++) {
#pragma unroll
      for (int reg = 0; reg < 4; reg++) {
        int o = otile * 128 + wr * 64 + mi * 16 + r4 * 4 + reg;
        float s = G0[o] * rsqrtf(V0[o] + 1e-5f);
        float sh = B0[o] - M0[o] * s;
#pragma unroll
        for (int ni = 0; ni < 4; ni++) {
          int p = ptile * 128 + wc * 64 + ni * 16 + cl;
          if (p >= P) continue;
          int bI = p / L, l = p - bI * L;
          float y = acc[mi][ni][reg] * s + sh;
          if (l < CW) out[((size_t)bI * CC + o) * CW + l] = y;
        }
      }
    }
  }
}

// One 64-lane wave per group of BASE positions spaced by `stride`.
// q,k: (b,NH,L,64); v: (b,L,256) position-major, head channel = nh*32+dd
template <int BASE>
__global__ __launch_bounds__(256) void attn_level(
    const float* __restrict__ q, const float* __restrict__ k,
    const float* __restrict__ vin, float* __restrict__ vout,
    int L, int stride, int gpb) {
  int lane = threadIdx.x & 63;
  int gid = blockIdx.x * 4 + (threadIdx.x >> 6);
  int bh = gid / gpb;
  int g = gid - bh * gpb;
  int bI = bh >> 3, nh = bh & 7;
  int i0 = g / stride;
  int k2 = g - i0 * stride;
  int posBase = i0 * BASE * stride + k2;
  size_t qkBase = ((size_t)bh * L + posBase) * KDd + lane;
  float qv[BASE], kv[BASE];
#pragma unroll
  for (int j = 0; j < BASE; j++) {
    qv[j] = q[qkBase + (size_t)j * stride * KDd];
    kv[j] = k[qkBase + (size_t)j * stride * KDd];
  }
  float sc[BASE * BASE];
#pragma unroll
  for (int J = 0; J < BASE; J++)
#pragma unroll
    for (int j = 0; j < BASE; j++) sc[J * BASE + j] = kv[J] * qv[j];
#pragma unroll
  for (int off = 1; off < 64; off <<= 1) {
#pragma unroll
    for (int t = 0; t < BASE * BASE; t++) sc[t] += __shfl_xor(sc[t], off, 64);
  }
#pragma unroll
  for (int J = 0; J < BASE; J++) {
    float mx = sc[J * BASE + 0];
#pragma unroll
    for (int j = 1; j < BASE; j++) mx = fmaxf(mx, sc[J * BASE + j]);
    float sum = 0.f;
#pragma unroll
    for (int j = 0; j < BASE; j++) {
      float e = __expf((sc[J * BASE + j] - mx) * 0.125f);
      sc[J * BASE + j] = e;
      sum += e;
    }
    float inv = 1.f / sum;
#pragma unroll
    for (int j = 0; j < BASE; j++) sc[J * BASE + j] *= inv;
  }
  int dd = lane & 31, half = lane >> 5;
  size_t vBase = ((size_t)bI * L + posBase) * CC + nh * HDd + dd;
  float vv[BASE];
#pragma unroll
  for (int j = 0; j < BASE; j++)
    vv[j] = vin[vBase + (size_t)j * stride * CC];
#pragma unroll
  for (int J = 0; J < BASE; J++) {
    if ((J & 1) == half) {
      float acc = 0.f;
#pragma unroll
      for (int j = 0; j < BASE; j++) acc += sc[J * BASE + j] * vv[j];
      vout[vBase + (size_t)J * stride * CC] = acc;
    }
  }
}

// xcur(b,CW,256) += v2(pos-major) + BN(dwconv3(v0pm)), channel-fastest threads
__global__ __launch_bounds__(256) void combine(
    float* __restrict__ xcur, const float* __restrict__ v0pm,
    const float* __restrict__ vfin, const float* __restrict__ peW,
    const float* __restrict__ G, const float* __restrict__ Bb,
    const float* __restrict__ M, const float* __restrict__ V, int L) {
  int idx = blockIdx.x * 256 + threadIdx.x;
  if (idx >= CB * CC * CW) return;
  int ch = idx & 255;
  int t = idx >> 8;
  int l = t % CW;
  int bI = t / CW;
  size_t row = ((size_t)bI * L + l) * CC + ch;
  float left = (l > 0) ? v0pm[row - CC] : 0.f;
  float mid = v0pm[row];
  float right = (l + 1 < L) ? v0pm[row + CC] : 0.f;
  float conv = left * peW[ch * 3 + 0] + mid * peW[ch * 3 + 1] + right * peW[ch * 3 + 2];
  float s = G[ch] * rsqrtf(V[ch] + 1e-5f);
  float pe = conv * s + (Bb[ch] - M[ch] * s);
  float v2 = vfin[row];
  xcur[((size_t)bI * CW + l) * CC + ch] += v2 + pe;
}

extern "C" void kernel_launch(void* const* d_in, const int* in_sizes, int n_in,
                              void* d_out, int out_size, void* d_ws, size_t ws_size,
                              hipStream_t stream) {
  const float* x = (const float*)d_in[0];
  const float* qk_W = (const float*)d_in[1];
  const float* qk_g = (const float*)d_in[2];
  const float* qk_b = (const float*)d_in[3];
  const float* qk_m = (const float*)d_in[4];
  const float* qk_v = (const float*)d_in[5];
  const float* v_W = (const float*)d_in[6];
  const float* v_g = (const float*)d_in[7];
  const float* v_b = (const float*)d_in[8];
  const float* v_m = (const float*)d_in[9];
  const float* v_v = (const float*)d_in[10];
  const float* pe_W = (const float*)d_in[11];
  const float* pe_g = (const float*)d_in[12];
  const float* pe_b = (const float*)d_in[13];
  const float* pe_m = (const float*)d_in[14];
  const float* pe_v = (const float*)d_in[15];
  const float* proj_W = (const float*)d_in[16];
  const float* proj_g = (const float*)d_in[17];
  const float* proj_b = (const float*)d_in[18];
  const float* proj_m = (const float*)d_in[19];
  const float* proj_v = (const float*)d_in[20];

  char* ws = (char*)d_ws;
  size_t off = 0;
  auto alloc = [&](size_t bytes) {
    char* p = ws + off;
    off += (bytes + 255) & ~(size_t)255;
    return (float*)p;
  };
  const int Lmax = 4096;
  float* xcur = alloc((size_t)CB * CW * CC * 4);     // position-major
  float* qbuf = alloc((size_t)CB * NHh * Lmax * KDd * 4);
  float* kbuf = alloc((size_t)CB * NHh * Lmax * KDd * 4);
  float* v0pm = alloc((size_t)CB * Lmax * CC * 4);   // position-major
  float* vA = alloc((size_t)CB * Lmax * CC * 4);     // aliases Ximg during GEMM
  float* vB = alloc((size_t)CB * Lmax * CC * 4);
  unsigned short* Wimg = (unsigned short*)alloc((size_t)10 * 16 * 8192);
  unsigned short* Ximg = (unsigned short*)vA;
  (void)ws_size;

  {
    dim3 gt((CW + 63) / 64, 4, CB);
    transpose_x<<<gt, 256, 0, stream>>>(x, xcur);
  }

  const int bases[2] = {5, 4};
  const int ns[2] = {5, 6};
  const int Ls[2] = {3125, 4096};
  int nElems = CB * CC * CW;
  for (int blk = 0; blk < 2; blk++) {
    int base = bases[blk], n = ns[blk], L = Ls[blk];
    int P = CB * L;
    int ptiles = (P + 127) / 128;
    prep_w<<<(1280 * 32 + 255) / 256, 256, 0, stream>>>(
        qk_W + (size_t)blk * 1024 * CC, 1024, v_W + (size_t)blk * CC * CC, Wimg, 1280);
    dim3 gx(ptiles, 4);
    prep_x<<<gx, 256, 0, stream>>>(xcur, Ximg, L, P);
    dim3 gg(ptiles, 10);
    gemm_bn<0><<<gg, 256, 0, stream>>>(
        Wimg, Ximg, qk_g + blk * 1024, qk_b + blk * 1024, qk_m + blk * 1024,
        qk_v + blk * 1024, v_g + blk * CC, v_b + blk * CC, v_m + blk * CC,
        v_v + blk * CC, qbuf, kbuf, v0pm, nullptr, L, P);

    const float* vin = v0pm;
    float* pp[2] = {vA, vB};
    int stride = 1;
    for (int i = 0; i < n - 1; i++) stride *= base;
    for (int i = 0; i < n; i++) {
      float* vo = pp[i & 1];
      int gpb = L / base;
      int totalg = CB * NHh * gpb;
      if (base == 5)
        attn_level<5><<<totalg / 4, 256, 0, stream>>>(qbuf, kbuf, vin, vo, L, stride, gpb);
      else
        attn_level<4><<<totalg / 4, 256, 0, stream>>>(qbuf, kbuf, vin, vo, L, stride, gpb);
      vin = vo;
      stride /= base;
    }
    combine<<<(nElems + 255) / 256, 256, 0, stream>>>(
        xcur, v0pm, vin, pe_W + (size_t)blk * CC * 3, pe_g + blk * CC,
        pe_b + blk * CC, pe_m + blk * CC, pe_v + blk * CC, L);
  }
  {
    int L = CW, P = CB * CW;
    int ptiles = (P + 127) / 128;
    prep_w<<<(256 * 32 + 255) / 256, 256, 0, stream>>>(proj_W, 256, nullptr, Wimg, 256);
    dim3 gx(ptiles, 4);
    prep_x<<<gx, 256, 0, stream>>>(xcur, Ximg, L, P);
    dim3 gg(ptiles, 2);
    gemm_bn<2><<<gg, 256, 0, stream>>>(
        Wimg, Ximg, proj_g, proj_b, proj_m, proj_v, nullptr, nullptr, nullptr,
        nullptr, nullptr, nullptr, nullptr, (float*)d_out, L, P);
  }
}